// Round 11
// baseline (100.311 us; speedup 1.0000x reference)
//
#include <hip/hip_runtime.h>
#include <float.h>

#define N_SRC 20000
#define N_TAR 20000
#define TPB 256
#define T 8                       // targets per thread
#define TGT_PER_BLK (TPB * T)     // 2048
#define TBLK 10                   // ceil(20000 / 2048)
#define SC 100                    // source chunks; TBLK*SC = 1000 blocks
#define CHUNK 200                 // 100*200 = 20000 exactly
#define FBLOCKS ((N_TAR + TPB - 1) / TPB)   // 79

// q = 0.5*||s||^2 - t.s  so that 0.5*d2 = 0.5*||t||^2 + q.
//
// r7-r10 post-mortem: the 2x-over-issue-floor plateau tracks the DEPENDENT
// FMA GAP inside the asm blocks (r7 gap-0 -> 2.2x, r10 gap-1 -> 2.4x), not
// registers (r8), not the data path (r9 global, r7/r10 LDS). v_fma latency
// ~4 cyc vs 2-cyc issue; waves are in-order and asm blocks atomic, so gap<2
// stalls every instruction. STEP4 interleaves 4 independent chains
// (2 sources x 2 targets): 12 fma in three rounds of 4 + 2 v_min3,
// dependent gap = 3 instr >= 6 cyc -> single-wave stall-free.

#define DECL(j) \
    const int ti##j = min(tbase + (j) * TPB, N_TAR - 1); \
    const float ntx##j = -tar[ti##j * 3 + 0]; \
    const float nty##j = -tar[ti##j * 3 + 1]; \
    const float ntz##j = -tar[ti##j * 3 + 2]; \
    float m##j = FLT_MAX;

// 2 sources (a,b) x 2 targets (j,k): 4 independent q-chains, gap-3 spacing.
#define STEP4(j, k, a, b) { float qaj, qbj, qak, qbk; \
    asm("v_fma_f32 %2, %7, %12, %8\n\t"  \
        "v_fma_f32 %3, %9, %12, %10\n\t" \
        "v_fma_f32 %4, %7, %15, %8\n\t"  \
        "v_fma_f32 %5, %9, %15, %10\n\t" \
        "v_fma_f32 %2, %11, %13, %2\n\t" \
        "v_fma_f32 %3, %6, %13, %3\n\t"  \
        "v_fma_f32 %4, %11, %16, %4\n\t" \
        "v_fma_f32 %5, %6, %16, %5\n\t"  \
        "v_fma_f32 %2, %14, %17, %2\n\t" \
        "v_fma_f32 %3, %18, %17, %3\n\t" \
        "v_fma_f32 %4, %14, %19, %4\n\t" \
        "v_fma_f32 %5, %18, %19, %5\n\t" \
        "v_min3_f32 %0, %0, %2, %3\n\t"  \
        "v_min3_f32 %1, %1, %4, %5"      \
        : "+v"(m##j), "+v"(m##k), \
          "=&v"(qaj), "=&v"(qbj), "=&v"(qak), "=&v"(qbk) \
        : "v"((b).y),                          /* %6  */ \
          "v"((a).z), "v"((a).w),              /* %7 %8 */ \
          "v"((b).z), "v"((b).w),              /* %9 %10 */ \
          "v"((a).y),                          /* %11 */ \
          "v"(ntz##j), "v"(nty##j),            /* %12 %13 */ \
          "v"((a).x),                          /* %14 */ \
          "v"(ntz##k), "v"(nty##k),            /* %15 %16 */ \
          "v"(ntx##j),                         /* %17 */ \
          "v"((b).x),                          /* %18 */ \
          "v"(ntx##k));                        /* %19 */ }

#define GROUP(a, b) { \
    STEP4(0, 1, a, b) STEP4(2, 3, a, b) STEP4(4, 5, a, b) STEP4(6, 7, a, b) }

#define STORE(j) \
    { const int t = tbase + (j) * TPB; if (t < N_TAR) part[c * N_TAR + t] = m##j; }

__global__
__attribute__((amdgpu_flat_work_group_size(TPB, TPB)))
__attribute__((amdgpu_waves_per_eu(4, 4)))
void nn_partial_min(
    const float* __restrict__ src, const float* __restrict__ tar,
    float* __restrict__ part, float* __restrict__ out)
{
    if (blockIdx.x == 0 && blockIdx.y == 0 && threadIdx.x == 0) out[0] = 0.f;

    __shared__ float4 sh[CHUNK];
    const int c = blockIdx.y;
    const int base = c * CHUNK;
    for (int i = threadIdx.x; i < CHUNK; i += TPB) {
        const int s = base + i;
        if (s < N_SRC) {
            const float x = src[s * 3 + 0];
            const float y = src[s * 3 + 1];
            const float z = src[s * 3 + 2];
            sh[i] = make_float4(x, y, z, 0.5f * (x * x + y * y + z * z));
        }
    }
    __syncthreads();

    const int tbase = blockIdx.x * TGT_PER_BLK + threadIdx.x;
    DECL(0) DECL(1) DECL(2) DECL(3) DECL(4) DECL(5) DECL(6) DECL(7)

    // Software pipeline: compute on (A0,A1)/(B0,B1) while the next four
    // sources are in flight. CHUNK=200: loop i=0..192 step 4 covers
    // sources 0..195 and leaves A=sh[196,197], B=sh[198,199] for the tail.
    float4 A0 = sh[0], A1 = sh[1], B0 = sh[2], B1 = sh[3];
#pragma unroll 1
    for (int i = 0; i + 4 < CHUNK; i += 4) {
        GROUP(A0, A1)
        A0 = sh[i + 4]; A1 = sh[i + 5];
        GROUP(B0, B1)
        B0 = sh[i + 6]; B1 = sh[i + 7];
    }
    GROUP(A0, A1)
    GROUP(B0, B1)

    STORE(0) STORE(1) STORE(2) STORE(3) STORE(4) STORE(5) STORE(6) STORE(7)
}

// Kernel 2: combine the SC chunk-mins per target, add 0.5*||t||^2,
// block-reduce, one atomicAdd per block into out[0] (zeroed by kernel 1).
__global__ __launch_bounds__(TPB) void nn_finalize(
    const float* __restrict__ tar, const float* __restrict__ part,
    float* __restrict__ out)
{
    const int t = blockIdx.x * TPB + threadIdx.x;
    float contrib = 0.f;
    if (t < N_TAR) {
        float m = FLT_MAX;
#pragma unroll
        for (int c = 0; c < SC; ++c) m = fminf(m, part[c * N_TAR + t]);
        const float tx = tar[t * 3 + 0];
        const float ty = tar[t * 3 + 1];
        const float tz = tar[t * 3 + 2];
        contrib = 0.5f * (tx * tx + ty * ty + tz * tz) + m;
    }
    for (int off = 32; off > 0; off >>= 1)
        contrib += __shfl_down(contrib, off);
    __shared__ float red[TPB / 64];
    if ((threadIdx.x & 63) == 0) red[threadIdx.x >> 6] = contrib;
    __syncthreads();
    if (threadIdx.x == 0) {
        float s = 0.f;
#pragma unroll
        for (int w = 0; w < TPB / 64; ++w) s += red[w];
        atomicAdd(out, s);
    }
}

extern "C" void kernel_launch(void* const* d_in, const int* in_sizes, int n_in,
                              void* d_out, int out_size, void* d_ws, size_t ws_size,
                              hipStream_t stream) {
    const float* src = (const float*)d_in[0];  // [20000,3] fp32
    const float* tar = (const float*)d_in[1];  // [20000,3] fp32
    float* out = (float*)d_out;                // scalar fp32
    float* part = (float*)d_ws;                // SC * N_TAR floats = 8 MB

    dim3 grid1(TBLK, SC);
    nn_partial_min<<<grid1, TPB, 0, stream>>>(src, tar, part, out);
    nn_finalize<<<FBLOCKS, TPB, 0, stream>>>(tar, part, out);
}

// Round 12
// 76.972 us; speedup vs baseline: 1.3032x; 1.3032x over previous
//
#include <hip/hip_runtime.h>
#include <float.h>

#define N_SRC 20000
#define N_TAR 20000
#define TPB 512                    // 8 waves/block
#define SPLITS 16                  // source splits (grid.y)
#define TILES 40                   // 32-source tiles per split; 16*40*32 = 20480 >= 20000
#define TGRP 79                    // target-strip groups (grid.x); 79*8 strips*32 = 20224 >= 20000
#define FBLOCKS ((N_TAR + 255) / 256)

typedef _Float16 half8 __attribute__((ext_vector_type(8)));
typedef float floatx16 __attribute__((ext_vector_type(16)));

// q(t,s) = 0.5||s||^2 - t.s, so 0.5*d2 = 0.5||t||^2 + q.
// One mfma_f32_32x32x16_f16 computes a 32x32 tile of q directly:
//   A row (target t): k0-8 = -t split-f16 cross terms, k9-10 = 1.0
//   B col (source s): k0-8 = s split-f16 terms,        k9-10 = split 0.5||s||^2
// split-f16 (hi/lo) keeps |q error| ~5e-6 (dropped lo*lo only).
// A layout: A[m=lane&31][k=(lane>>5)*8+j]; B[k=(lane>>5)*8+j][n=lane&31];
// C/D: col=lane&31, row=(reg&3)+8*(reg>>2)+4*(lane>>5)  [m74/m101].
__global__ __launch_bounds__(TPB) void nn_mfma(
    const float* __restrict__ src, const float* __restrict__ tar,
    float* __restrict__ part, float* __restrict__ out)
{
    if (blockIdx.x == 0 && blockIdx.y == 0 && threadIdx.x == 0) out[0] = 0.f;

    __shared__ alignas(16) _Float16 lds[TILES * 32 * 16];  // 40 KB

    const int tid  = threadIdx.x;
    const int lane = tid & 63;
    const int col  = lane & 31;
    const int half = (lane >> 5) & 1;
    const int wave = tid >> 6;

    // ---- stage B fragments for this split's 1280 sources ----
    const int sbase = blockIdx.y * (TILES * 32);
    for (int ls = tid; ls < TILES * 32; ls += TPB) {
        const int s = sbase + ls;
        half8 f0 = {0, 0, 0, 0, 0, 0, 0, 0};
        half8 f1 = {0, 0, 0, 0, 0, 0, 0, 0};
        if (s < N_SRC) {
            const float x = src[s * 3 + 0];
            const float y = src[s * 3 + 1];
            const float z = src[s * 3 + 2];
            const _Float16 xh = (_Float16)x, yh = (_Float16)y, zh = (_Float16)z;
            const _Float16 xl = (_Float16)(x - (float)xh);
            const _Float16 yl = (_Float16)(y - (float)yh);
            const _Float16 zl = (_Float16)(z - (float)zh);
            const float nrm = 0.5f * (x * x + y * y + z * z);
            const _Float16 nh = (_Float16)nrm;
            const _Float16 nl = (_Float16)(nrm - (float)nh);
            f0 = (half8){xh, yh, zh, xh, yh, zh, xl, yl};
            f1 = (half8){zl, nh, nl, 0, 0, 0, 0, 0};
        } else {
            f1 = (half8){0, (_Float16)30000.f, 0, 0, 0, 0, 0, 0}; // never the min
        }
        *(half8*)&lds[ls * 16 + 0] = f0;
        *(half8*)&lds[ls * 16 + 8] = f1;
    }

    // ---- build A fragment: this wave's 32 targets ----
    const int strip = blockIdx.x * 8 + wave;
    const int t = min(strip * 32 + col, N_TAR - 1);
    const float tx = tar[t * 3 + 0];
    const float ty = tar[t * 3 + 1];
    const float tz = tar[t * 3 + 2];
    const _Float16 txh = (_Float16)tx, tyh = (_Float16)ty, tzh = (_Float16)tz;
    const _Float16 txl = (_Float16)(tx - (float)txh);
    const _Float16 tyl = (_Float16)(ty - (float)tyh);
    const _Float16 tzl = (_Float16)(tz - (float)tzh);
    half8 a;
    if (half == 0)
        a = (half8){-txh, -tyh, -tzh, -txl, -tyl, -tzl, -txh, -tyh};
    else
        a = (half8){-tzh, (_Float16)1.f, (_Float16)1.f, 0, 0, 0, 0, 0};

    __syncthreads();

    // ---- scan tiles: 1 ds_read_b128 + 1 mfma + 16 v_min per 1024 pairs ----
    floatx16 m;
#pragma unroll
    for (int i = 0; i < 16; ++i) m[i] = FLT_MAX;
    const floatx16 zero = {};  // all-zero accumulator init
    const int foff = col * 16 + half * 8;
#pragma unroll 2
    for (int tile = 0; tile < TILES; ++tile) {
        const half8 b = *(const half8*)&lds[tile * 512 + foff];
        const floatx16 d = __builtin_amdgcn_mfma_f32_32x32x16_f16(a, b, zero, 0, 0, 0);
#pragma unroll
        for (int i = 0; i < 16; ++i) m[i] = fminf(m[i], d[i]);
    }

    // ---- min over the 32 columns (per 32-lane half), then store ----
#pragma unroll
    for (int i = 0; i < 16; ++i) {
        m[i] = fminf(m[i], __shfl_xor(m[i], 1));
        m[i] = fminf(m[i], __shfl_xor(m[i], 2));
        m[i] = fminf(m[i], __shfl_xor(m[i], 4));
        m[i] = fminf(m[i], __shfl_xor(m[i], 8));
        m[i] = fminf(m[i], __shfl_xor(m[i], 16));
    }
    if (col == 0) {
#pragma unroll
        for (int i = 0; i < 16; ++i) {
            const int row = (i & 3) + 8 * (i >> 2) + 4 * half;
            const int tt = min(strip * 32 + row, N_TAR - 1);
            part[blockIdx.y * N_TAR + tt] = m[i];
        }
    }
}

// combine the SPLITS mins per target, add 0.5||t||^2, reduce into out[0]
__global__ __launch_bounds__(256) void nn_finalize(
    const float* __restrict__ tar, const float* __restrict__ part,
    float* __restrict__ out)
{
    const int t = blockIdx.x * 256 + threadIdx.x;
    float contrib = 0.f;
    if (t < N_TAR) {
        float m = FLT_MAX;
#pragma unroll
        for (int c = 0; c < SPLITS; ++c) m = fminf(m, part[c * N_TAR + t]);
        const float tx = tar[t * 3 + 0];
        const float ty = tar[t * 3 + 1];
        const float tz = tar[t * 3 + 2];
        contrib = 0.5f * (tx * tx + ty * ty + tz * tz) + m;
    }
    for (int off = 32; off > 0; off >>= 1)
        contrib += __shfl_down(contrib, off);
    __shared__ float red[4];
    if ((threadIdx.x & 63) == 0) red[threadIdx.x >> 6] = contrib;
    __syncthreads();
    if (threadIdx.x == 0) {
        float s = 0.f;
#pragma unroll
        for (int w = 0; w < 4; ++w) s += red[w];
        atomicAdd(out, s);
    }
}

extern "C" void kernel_launch(void* const* d_in, const int* in_sizes, int n_in,
                              void* d_out, int out_size, void* d_ws, size_t ws_size,
                              hipStream_t stream) {
    const float* src = (const float*)d_in[0];  // [20000,3] fp32
    const float* tar = (const float*)d_in[1];  // [20000,3] fp32
    float* out = (float*)d_out;                // scalar fp32
    float* part = (float*)d_ws;                // SPLITS * N_TAR floats = 1.28 MB

    dim3 grid1(TGRP, SPLITS);
    nn_mfma<<<grid1, TPB, 0, stream>>>(src, tar, part, out);
    nn_finalize<<<FBLOCKS, 256, 0, stream>>>(tar, part, out);
}